// Round 2
// baseline (757.122 us; speedup 1.0000x reference)
//
#include <hip/hip_runtime.h>
#include <math.h>

#define HDIM 32
#define SDOM 32

__device__ __forceinline__ float fast_sigmoid(float z) {
    return 1.0f / (1.0f + __expf(-z));
}

__device__ __forceinline__ float fast_tanh(float z) {
    // tanh(z) = 1 - 2/(exp(2z)+1); exact at 0, correct saturation at +/-inf
    return 1.0f - 2.0f / (__expf(2.0f * z) + 1.0f);
}

__global__ __launch_bounds__(256) void fbpinn_kernel(
    const float* __restrict__ X,
    const float* __restrict__ centers,
    const float* __restrict__ widths,
    const float* __restrict__ core_min,
    const float* __restrict__ core_max,
    const float* __restrict__ overlap,
    const float* __restrict__ W1,
    const float* __restrict__ b1,
    const float* __restrict__ W2,
    const float* __restrict__ b2,
    const float* __restrict__ W3,
    const float* __restrict__ b3,
    const float* __restrict__ Wout,
    const float* __restrict__ bout,
    const float* __restrict__ scale,
    const float* __restrict__ shift,
    float* __restrict__ out,
    int n_pts)
{
    const int n = blockIdx.x * blockDim.x + threadIdx.x;
    if (n >= n_pts) return;

    const float t = X[2 * n + 0];
    const float x = X[2 * n + 1];

    const float sc = scale[0];
    const float sh = shift[0];

    float num = 0.0f;
    float den = 0.0f;

    for (int s = 0; s < SDOM; ++s) {
        // ---- window weight (product of sigmoid gates over D=2 dims) ----
        float w = 1.0f;
        float xn0, xn1;
        {
            // d = 0 (time)
            float wid = widths[s * 2 + 0];
            float sd = 4.0f / (2.0f * overlap[s * 2 + 0] * wid + 1e-8f);
            float l = fast_sigmoid(sd * (t - core_min[s * 2 + 0]));
            float r = fast_sigmoid(sd * (core_max[s * 2 + 0] - t));
            w *= l * r;
            xn0 = (t - centers[s * 2 + 0]) / wid + 0.5f;
            // d = 1 (space)
            wid = widths[s * 2 + 1];
            sd = 4.0f / (2.0f * overlap[s * 2 + 1] * wid + 1e-8f);
            l = fast_sigmoid(sd * (x - core_min[s * 2 + 1]));
            r = fast_sigmoid(sd * (core_max[s * 2 + 1] - x));
            w *= l * r;
            xn1 = (x - centers[s * 2 + 1]) / wid + 0.5f;
        }

        // ---- layer 1: (2 -> 32), tanh ----
        float h0[HDIM], h1a[HDIM];
        const float* W1s = W1 + s * 2 * HDIM;   // [d][h]
        const float* b1s = b1 + s * HDIM;
        #pragma unroll
        for (int j = 0; j < HDIM; ++j) {
            float a = fmaf(xn0, W1s[j], fmaf(xn1, W1s[HDIM + j], b1s[j]));
            h0[j] = fast_tanh(a);
        }

        // ---- layer 2: (32 -> 32), tanh ----
        const float* W2s = W2 + s * HDIM * HDIM;  // [i][j]
        const float* b2s = b2 + s * HDIM;
        #pragma unroll
        for (int j = 0; j < HDIM; ++j) h1a[j] = b2s[j];
        #pragma unroll
        for (int i = 0; i < HDIM; ++i) {
            float hv = h0[i];
            #pragma unroll
            for (int j = 0; j < HDIM; ++j)
                h1a[j] = fmaf(hv, W2s[i * HDIM + j], h1a[j]);
        }
        #pragma unroll
        for (int j = 0; j < HDIM; ++j) h1a[j] = fast_tanh(h1a[j]);

        // ---- layer 3: (32 -> 32), tanh fused into the output dot ----
        const float* W3s = W3 + s * HDIM * HDIM;
        const float* b3s = b3 + s * HDIM;
        #pragma unroll
        for (int j = 0; j < HDIM; ++j) h0[j] = b3s[j];
        #pragma unroll
        for (int i = 0; i < HDIM; ++i) {
            float hv = h1a[i];
            #pragma unroll
            for (int j = 0; j < HDIM; ++j)
                h0[j] = fmaf(hv, W3s[i * HDIM + j], h0[j]);
        }

        // ---- output layer: (32 -> 1) ----
        float y = bout[s];
        const float* Wos = Wout + s * HDIM;
        #pragma unroll
        for (int j = 0; j < HDIM; ++j)
            y = fmaf(fast_tanh(h0[j]), Wos[j], y);

        y = fmaf(sc, y, sh);
        num = fmaf(w, y, num);
        den += w;
    }

    const float u = num / (den + 1e-8f);

    // ---- ansatz epilogue ----
    const float factor = fast_tanh(x + 1.0f) * fast_tanh(x - 1.0f) * fast_tanh(t);
    const float pi = 3.14159265358979323846f;
    out[n] = fmaf(factor, u, -__sinf(pi * x));
}

extern "C" void kernel_launch(void* const* d_in, const int* in_sizes, int n_in,
                              void* d_out, int out_size, void* d_ws, size_t ws_size,
                              hipStream_t stream) {
    const float* X        = (const float*)d_in[0];
    const float* centers  = (const float*)d_in[1];
    const float* widths   = (const float*)d_in[2];
    const float* core_min = (const float*)d_in[3];
    const float* core_max = (const float*)d_in[4];
    const float* overlap  = (const float*)d_in[5];
    const float* W1       = (const float*)d_in[6];
    const float* b1       = (const float*)d_in[7];
    const float* W2       = (const float*)d_in[8];
    const float* b2       = (const float*)d_in[9];
    const float* W3       = (const float*)d_in[10];
    const float* b3       = (const float*)d_in[11];
    const float* Wout     = (const float*)d_in[12];
    const float* bout     = (const float*)d_in[13];
    const float* scale    = (const float*)d_in[14];
    const float* shift    = (const float*)d_in[15];

    float* out = (float*)d_out;
    const int n_pts = in_sizes[0] / 2;  // X is (N, 2)

    const int block = 256;
    const int grid = (n_pts + block - 1) / block;
    fbpinn_kernel<<<grid, block, 0, stream>>>(
        X, centers, widths, core_min, core_max, overlap,
        W1, b1, W2, b2, W3, b3, Wout, bout, scale, shift,
        out, n_pts);
}

// Round 3
// 390.193 us; speedup vs baseline: 1.9404x; 1.9404x over previous
//
#include <hip/hip_runtime.h>
#include <math.h>

typedef short    bf16x8 __attribute__((ext_vector_type(8)));
typedef float    f32x16 __attribute__((ext_vector_type(16)));
typedef float    f32x4  __attribute__((ext_vector_type(4)));
typedef unsigned int u32x4 __attribute__((ext_vector_type(4)));

__device__ __forceinline__ unsigned short f2bf(float f) {
    unsigned int u = __builtin_bit_cast(unsigned int, f);
    u = (u + 0x7FFFu + ((u >> 16) & 1u)) >> 16;   // RNE
    return (unsigned short)u;
}
__device__ __forceinline__ float bf2f(unsigned short h) {
    unsigned int u = ((unsigned int)h) << 16;
    return __builtin_bit_cast(float, u);
}
__device__ __forceinline__ float fast_sigmoid(float z) {
    return 1.0f / (1.0f + __expf(-z));
}
__device__ __forceinline__ float fast_tanh(float z) {
    return 1.0f - 2.0f / (__expf(2.0f * z) + 1.0f);
}

// rule-18 fence: wave-local LDS write->read ordering
#define LDS_FENCE() do { \
    asm volatile("s_waitcnt lgkmcnt(0)" ::: "memory"); \
    __builtin_amdgcn_sched_barrier(0); \
} while (0)

__global__ __launch_bounds__(256) void fbpinn_mfma(
    const float* __restrict__ X,
    const float* __restrict__ centers,
    const float* __restrict__ widths,
    const float* __restrict__ core_min,
    const float* __restrict__ core_max,
    const float* __restrict__ overlap,
    const float* __restrict__ W1,
    const float* __restrict__ b1,
    const float* __restrict__ W2,
    const float* __restrict__ b2,
    const float* __restrict__ W3,
    const float* __restrict__ b3,
    const float* __restrict__ Wout,
    const float* __restrict__ bout,
    const float* __restrict__ scale,
    const float* __restrict__ shift,
    float* __restrict__ out,
    int n_pts)
{
    __shared__ __align__(16) unsigned short sW1[64];     // [d][j]
    __shared__ __align__(16) float          sB1[32];
    __shared__ __align__(16) unsigned short sW2t[1024];  // swizzled [j][k]
    __shared__ __align__(16) float          sB2[32];
    __shared__ __align__(16) unsigned short sW3t[1024];  // swizzled [j][k]
    __shared__ __align__(16) float          sB3[32];
    __shared__ __align__(16) float          sWout[32];
    __shared__ float                        sBout[1];
    __shared__ float                        sWin[32][2][5]; // {sd, cmin, cmax, ctr, 1/wid}
    __shared__ __align__(16) unsigned short sH[4][1024]; // per-wave h tile, swizzled [row][k]

    const int tid  = threadIdx.x;
    const int wave = tid >> 6;
    const int lane = tid & 63;
    const int p    = lane & 31;   // point-row within wave tile; also C/D col id
    const int half = lane >> 5;   // k-group / row-group selector

    int P = blockIdx.x * 128 + wave * 32 + p;
    if (P >= n_pts) P = n_pts - 1;  // grid is exact for N=131072; safety clamp only

    const float t  = X[2 * P + 0];
    const float x  = X[2 * P + 1];
    const float sc = scale[0];
    const float sh = shift[0];

    // one-time window-parameter precompute
    if (tid < 64) {
        int ss = tid >> 1, d = tid & 1;
        float wid = widths[ss * 2 + d];
        float ov  = overlap[ss * 2 + d];
        sWin[ss][d][0] = 4.0f / (2.0f * ov * wid + 1e-8f);
        sWin[ss][d][1] = core_min[ss * 2 + d];
        sWin[ss][d][2] = core_max[ss * 2 + d];
        sWin[ss][d][3] = centers[ss * 2 + d];
        sWin[ss][d][4] = 1.0f / wid;
    }

    float num = 0.0f, den = 0.0f;
    unsigned short* hbuf = &sH[wave][0];

    for (int s = 0; s < 32; ++s) {
        __syncthreads();   // previous iteration's consumers done
        // ---- stage subdomain-s weights into LDS (bf16 W, f32 biases) ----
        {
            const float* W2s = W2 + s * 1024;
            const float* W3s = W3 + s * 1024;
            #pragma unroll
            for (int i = 0; i < 4; ++i) {
                int e = tid + (i << 8);        // e = k*32 + j
                int k = e >> 5, j = e & 31;
                int di = (j << 5) + (k ^ ((j & 3) << 3));  // transposed + XOR swizzle
                sW2t[di] = f2bf(W2s[e]);
                sW3t[di] = f2bf(W3s[e]);
            }
            if (tid < 64)       sW1[tid]        = f2bf(W1[s * 64 + tid]);
            else if (tid < 96)  sB1[tid - 64]   = b1[s * 32 + (tid - 64)];
            else if (tid < 128) sB2[tid - 96]   = b2[s * 32 + (tid - 96)];
            else if (tid < 160) sB3[tid - 128]  = b3[s * 32 + (tid - 128)];
            else if (tid < 192) sWout[tid - 160] = Wout[s * 32 + (tid - 160)];
            else if (tid == 192) sBout[0]       = bout[s];
        }
        __syncthreads();

        // ---- window + normalized coords (f32 VALU) ----
        float sd0 = sWin[s][0][0], cm0 = sWin[s][0][1], cx0 = sWin[s][0][2],
              ct0 = sWin[s][0][3], rw0 = sWin[s][0][4];
        float sd1 = sWin[s][1][0], cm1 = sWin[s][1][1], cx1 = sWin[s][1][2],
              ct1 = sWin[s][1][3], rw1 = sWin[s][1][4];
        float w = fast_sigmoid(sd0 * (t - cm0)) * fast_sigmoid(sd0 * (cx0 - t))
                * fast_sigmoid(sd1 * (x - cm1)) * fast_sigmoid(sd1 * (cx1 - x));
        float xn0 = (t - ct0) * rw0 + 0.5f;
        float xn1 = (x - ct1) * rw1 + 0.5f;

        // ---- layer 1 (VALU): lane -> point p, hidden j = half*16 + jj ----
        {
            bf16x8 w0a = *(bf16x8*)&sW1[half * 16];
            bf16x8 w0b = *(bf16x8*)&sW1[half * 16 + 8];
            bf16x8 w1a = *(bf16x8*)&sW1[32 + half * 16];
            bf16x8 w1b = *(bf16x8*)&sW1[32 + half * 16 + 8];
            f32x4 bb0 = *(f32x4*)&sB1[half * 16 + 0];
            f32x4 bb1 = *(f32x4*)&sB1[half * 16 + 4];
            f32x4 bb2 = *(f32x4*)&sB1[half * 16 + 8];
            f32x4 bb3 = *(f32x4*)&sB1[half * 16 + 12];

            float Wa[16], Wb[16], Bv[16];
            #pragma unroll
            for (int i = 0; i < 8; ++i) {
                Wa[i]     = bf2f((unsigned short)w0a[i]);
                Wa[8 + i] = bf2f((unsigned short)w0b[i]);
                Wb[i]     = bf2f((unsigned short)w1a[i]);
                Wb[8 + i] = bf2f((unsigned short)w1b[i]);
            }
            #pragma unroll
            for (int i = 0; i < 4; ++i) {
                Bv[i]      = bb0[i];
                Bv[4 + i]  = bb1[i];
                Bv[8 + i]  = bb2[i];
                Bv[12 + i] = bb3[i];
            }

            unsigned int pk[8];
            #pragma unroll
            for (int q = 0; q < 8; ++q) {
                int j0 = 2 * q, j1 = 2 * q + 1;
                float a0 = fmaf(xn0, Wa[j0], fmaf(xn1, Wb[j0], Bv[j0]));
                float a1 = fmaf(xn0, Wa[j1], fmaf(xn1, Wb[j1], Bv[j1]));
                pk[q] = (unsigned int)f2bf(fast_tanh(a0))
                      | ((unsigned int)f2bf(fast_tanh(a1)) << 16);
            }
            u32x4 pk0 = { pk[0], pk[1], pk[2], pk[3] };
            u32x4 pk1 = { pk[4], pk[5], pk[6], pk[7] };
            int base0 = (p << 5) + ((half * 16)     ^ ((p & 3) << 3));
            int base1 = (p << 5) + ((half * 16 + 8) ^ ((p & 3) << 3));
            *(u32x4*)&hbuf[base0] = pk0;
            *(u32x4*)&hbuf[base1] = pk1;
        }
        LDS_FENCE();

        // fragment offsets (identical formula for A from hbuf and B from sW*t)
        const int ef0 = (p << 5) + ((half * 8)      ^ ((p & 3) << 3)); // k = 0..15 slice
        const int ef1 = (p << 5) + ((16 + half * 8) ^ ((p & 3) << 3)); // k = 16..31 slice

        // ---- layer 2 (MFMA) ----
        {
            bf16x8 bf0 = *(bf16x8*)&sW2t[ef0];
            bf16x8 bf1 = *(bf16x8*)&sW2t[ef1];
            bf16x8 a0  = *(bf16x8*)&hbuf[ef0];
            bf16x8 a1  = *(bf16x8*)&hbuf[ef1];
            float bj = sB2[p];
            f32x16 acc;
            #pragma unroll
            for (int r = 0; r < 16; ++r) acc[r] = bj;
            acc = __builtin_amdgcn_mfma_f32_32x32x16_bf16(a0, bf0, acc, 0, 0, 0);
            acc = __builtin_amdgcn_mfma_f32_32x32x16_bf16(a1, bf1, acc, 0, 0, 0);
            #pragma unroll
            for (int r = 0; r < 16; ++r) {
                int row = (r & 3) + ((r >> 2) << 3) + (half << 2);
                hbuf[(row << 5) + (p ^ ((r & 3) << 3))] = f2bf(fast_tanh(acc[r]));
            }
        }
        LDS_FENCE();

        // ---- layer 3 (MFMA) ----
        {
            bf16x8 bf0 = *(bf16x8*)&sW3t[ef0];
            bf16x8 bf1 = *(bf16x8*)&sW3t[ef1];
            bf16x8 a0  = *(bf16x8*)&hbuf[ef0];
            bf16x8 a1  = *(bf16x8*)&hbuf[ef1];
            float bj = sB3[p];
            f32x16 acc;
            #pragma unroll
            for (int r = 0; r < 16; ++r) acc[r] = bj;
            acc = __builtin_amdgcn_mfma_f32_32x32x16_bf16(a0, bf0, acc, 0, 0, 0);
            acc = __builtin_amdgcn_mfma_f32_32x32x16_bf16(a1, bf1, acc, 0, 0, 0);
            #pragma unroll
            for (int r = 0; r < 16; ++r) {
                int row = (r & 3) + ((r >> 2) << 3) + (half << 2);
                hbuf[(row << 5) + (p ^ ((r & 3) << 3))] = f2bf(fast_tanh(acc[r]));
            }
        }
        LDS_FENCE();

        // ---- output dot (VALU): lane -> point p, hidden half ----
        {
            int eo0 = (p << 5) + ((half * 16)     ^ ((p & 3) << 3));
            int eo1 = (p << 5) + ((half * 16 + 8) ^ ((p & 3) << 3));
            bf16x8 h3a = *(bf16x8*)&hbuf[eo0];
            bf16x8 h3b = *(bf16x8*)&hbuf[eo1];
            f32x4 wo0 = *(f32x4*)&sWout[half * 16 + 0];
            f32x4 wo1 = *(f32x4*)&sWout[half * 16 + 4];
            f32x4 wo2 = *(f32x4*)&sWout[half * 16 + 8];
            f32x4 wo3 = *(f32x4*)&sWout[half * 16 + 12];
            float Wo[16];
            #pragma unroll
            for (int i = 0; i < 4; ++i) {
                Wo[i]      = wo0[i];
                Wo[4 + i]  = wo1[i];
                Wo[8 + i]  = wo2[i];
                Wo[12 + i] = wo3[i];
            }
            float yp = 0.0f;
            #pragma unroll
            for (int i = 0; i < 8; ++i) yp = fmaf(bf2f((unsigned short)h3a[i]), Wo[i], yp);
            #pragma unroll
            for (int i = 0; i < 8; ++i) yp = fmaf(bf2f((unsigned short)h3b[i]), Wo[8 + i], yp);
            float y = yp + __shfl_xor(yp, 32, 64);   // combine the two hidden halves
            y += sBout[0];
            y = fmaf(sc, y, sh);
            num = fmaf(w, y, num);
            den += w;
        }
    }

    // ---- normalize + ansatz epilogue ----
    const float u = num / (den + 1e-8f);
    if (half == 0) {
        float fac = fast_tanh(x + 1.0f) * fast_tanh(x - 1.0f) * fast_tanh(t);
        const float pi = 3.14159265358979323846f;
        out[P] = fmaf(fac, u, -__sinf(pi * x));
    }
}

extern "C" void kernel_launch(void* const* d_in, const int* in_sizes, int n_in,
                              void* d_out, int out_size, void* d_ws, size_t ws_size,
                              hipStream_t stream) {
    const float* X        = (const float*)d_in[0];
    const float* centers  = (const float*)d_in[1];
    const float* widths   = (const float*)d_in[2];
    const float* core_min = (const float*)d_in[3];
    const float* core_max = (const float*)d_in[4];
    const float* overlap  = (const float*)d_in[5];
    const float* W1       = (const float*)d_in[6];
    const float* b1       = (const float*)d_in[7];
    const float* W2       = (const float*)d_in[8];
    const float* b2       = (const float*)d_in[9];
    const float* W3       = (const float*)d_in[10];
    const float* b3       = (const float*)d_in[11];
    const float* Wout     = (const float*)d_in[12];
    const float* bout     = (const float*)d_in[13];
    const float* scale    = (const float*)d_in[14];
    const float* shift    = (const float*)d_in[15];

    float* out = (float*)d_out;
    const int n_pts = in_sizes[0] / 2;  // X is (N, 2)

    const int block = 256;
    const int grid = (n_pts + 127) / 128;  // 128 points per block (4 waves x 32)
    fbpinn_mfma<<<grid, block, 0, stream>>>(
        X, centers, widths, core_min, core_max, overlap,
        W1, b1, W2, b2, W3, b3, Wout, bout, scale, shift,
        out, n_pts);
}

// Round 4
// 347.599 us; speedup vs baseline: 2.1781x; 1.1225x over previous
//
#include <hip/hip_runtime.h>
#include <math.h>

typedef short    bf16x8 __attribute__((ext_vector_type(8)));
typedef float    f32x16 __attribute__((ext_vector_type(16)));
typedef float    f32x4  __attribute__((ext_vector_type(4)));
typedef unsigned int u32x4 __attribute__((ext_vector_type(4)));

// element-granular XOR swizzle: spreads 64B-stride rows across all 32 banks
// base bank(row) = (16*row + 4*((row>>1)&3)) mod 32 -> 8 distinct 4-bank windows
#define SWZ(row) ((((row) >> 1) & 3) << 3)

__device__ __forceinline__ unsigned short f2bf(float f) {
    unsigned int u = __builtin_bit_cast(unsigned int, f);
    u = (u + 0x7FFFu + ((u >> 16) & 1u)) >> 16;   // RNE
    return (unsigned short)u;
}
__device__ __forceinline__ unsigned int cvt_pk_bf16(float lo, float hi) {
    unsigned int r;
    asm("v_cvt_pk_bf16_f32 %0, %1, %2" : "=v"(r) : "v"(lo), "v"(hi));
    return r;   // lo -> bits[15:0], hi -> bits[31:16], RNE
}
__device__ __forceinline__ float fast_sigmoid(float z) {
    return 1.0f / (1.0f + __expf(-z));
}
__device__ __forceinline__ float fast_tanh(float z) {
    return 1.0f - 2.0f / (__expf(2.0f * z) + 1.0f);
}

// rule-18 fence: wave-local LDS write->read ordering
#define LDS_FENCE() do { \
    asm volatile("s_waitcnt lgkmcnt(0)" ::: "memory"); \
    __builtin_amdgcn_sched_barrier(0); \
} while (0)

// Each block: 128 points (4 waves x 32) x s_count subdomains (staged in
// chunks of 4). Partial (num, den) per point written to ws.
__global__ __launch_bounds__(256) void fbpinn_main(
    const float* __restrict__ X,
    const float* __restrict__ centers,
    const float* __restrict__ widths,
    const float* __restrict__ core_min,
    const float* __restrict__ core_max,
    const float* __restrict__ overlap,
    const float* __restrict__ W1,
    const float* __restrict__ b1,
    const float* __restrict__ W2,
    const float* __restrict__ b2,
    const float* __restrict__ W3,
    const float* __restrict__ b3,
    const float* __restrict__ Wout,
    const float* __restrict__ bout,
    float* __restrict__ ws,
    int n_pts, int s_count)
{
    __shared__ __align__(16) unsigned short sW2t[4][1024];  // swizzled [j][k]
    __shared__ __align__(16) unsigned short sW3t[4][1024];
    __shared__ __align__(16) unsigned short sW1[4][64];     // [d][j]
    __shared__ __align__(16) float sB1[4][32], sB2[4][32], sB3[4][32], sWo[4][32];
    __shared__ float sBout[4];
    __shared__ __align__(16) unsigned short sH[4][1024];    // per-wave tile [m][k]

    const int tid  = threadIdx.x;
    const int wave = tid >> 6;
    const int lane = tid & 63;
    const int p    = lane & 31;
    const int half = lane >> 5;
    const int s_begin = blockIdx.y * s_count;

    int P = blockIdx.x * 128 + wave * 32 + p;
    if (P >= n_pts) P = n_pts - 1;   // N=131072 divides exactly; safety only

    const float t = X[2 * P + 0];
    const float x = X[2 * P + 1];

    float num = 0.0f, den = 0.0f;
    unsigned short* hb = &sH[wave][0];

    for (int c0 = 0; c0 < s_count; c0 += 4) {
        __syncthreads();   // all waves done with previous chunk's weights
        // ---- stage 4 subdomains' weights (bf16 W, f32 biases) ----
        {
            const float* W2s = W2 + (size_t)(s_begin + c0) * 1024;
            const float* W3s = W3 + (size_t)(s_begin + c0) * 1024;
            #pragma unroll
            for (int i = 0; i < 16; ++i) {
                int e = tid + (i << 8);            // e = sl*1024 + k*32 + j
                int sl = e >> 10, r = e & 1023;
                int k = r >> 5, j = r & 31;
                int di = (j << 5) + (k ^ SWZ(j));  // transposed + swizzle
                sW2t[sl][di] = f2bf(W2s[e]);
                sW3t[sl][di] = f2bf(W3s[e]);
            }
            // W1: 4*64 elements
            sW1[tid >> 6][tid & 63] = f2bf(W1[(size_t)(s_begin + c0) * 64 + tid]);
            if (tid < 128) {
                int sl = tid >> 5, j = tid & 31;
                int g = (s_begin + c0 + sl) * 32 + j;
                sB1[sl][j] = b1[g];
                sB2[sl][j] = b2[g];
                sB3[sl][j] = b3[g];
                sWo[sl][j] = Wout[g];
            }
            if (tid < 4) sBout[tid] = bout[s_begin + c0 + tid];
        }
        __syncthreads();

        for (int si = 0; si < 4; ++si) {
            const int s = s_begin + c0 + si;

            // ---- window + normalized coords (params wave-uniform -> s_load) ----
            float wid0 = widths[s * 2 + 0], wid1 = widths[s * 2 + 1];
            float sd0 = 4.0f / (2.0f * overlap[s * 2 + 0] * wid0 + 1e-8f);
            float sd1 = 4.0f / (2.0f * overlap[s * 2 + 1] * wid1 + 1e-8f);
            float w = fast_sigmoid(sd0 * (t - core_min[s * 2 + 0]))
                    * fast_sigmoid(sd0 * (core_max[s * 2 + 0] - t))
                    * fast_sigmoid(sd1 * (x - core_min[s * 2 + 1]))
                    * fast_sigmoid(sd1 * (core_max[s * 2 + 1] - x));
            float xn0 = (t - centers[s * 2 + 0]) / wid0 + 0.5f;
            float xn1 = (x - centers[s * 2 + 1]) / wid1 + 0.5f;

            // ---- layer 1 (VALU): lane -> point p, hidden j = half*16 + 0..15 ----
            {
                bf16x8 w0a = *(bf16x8*)&sW1[si][half * 16];
                bf16x8 w0b = *(bf16x8*)&sW1[si][half * 16 + 8];
                bf16x8 w1a = *(bf16x8*)&sW1[si][32 + half * 16];
                bf16x8 w1b = *(bf16x8*)&sW1[si][32 + half * 16 + 8];
                f32x4 bb0 = *(f32x4*)&sB1[si][half * 16 + 0];
                f32x4 bb1 = *(f32x4*)&sB1[si][half * 16 + 4];
                f32x4 bb2 = *(f32x4*)&sB1[si][half * 16 + 8];
                f32x4 bb3 = *(f32x4*)&sB1[si][half * 16 + 12];

                float Wa[16], Wb[16], Bv[16];
                #pragma unroll
                for (int i = 0; i < 8; ++i) {
                    Wa[i]     = __builtin_bit_cast(float, ((unsigned int)(unsigned short)w0a[i]) << 16);
                    Wa[8 + i] = __builtin_bit_cast(float, ((unsigned int)(unsigned short)w0b[i]) << 16);
                    Wb[i]     = __builtin_bit_cast(float, ((unsigned int)(unsigned short)w1a[i]) << 16);
                    Wb[8 + i] = __builtin_bit_cast(float, ((unsigned int)(unsigned short)w1b[i]) << 16);
                }
                #pragma unroll
                for (int i = 0; i < 4; ++i) {
                    Bv[i] = bb0[i]; Bv[4 + i] = bb1[i]; Bv[8 + i] = bb2[i]; Bv[12 + i] = bb3[i];
                }

                unsigned int pk[8];
                #pragma unroll
                for (int q = 0; q < 8; ++q) {
                    float a0 = fmaf(xn0, Wa[2 * q],     fmaf(xn1, Wb[2 * q],     Bv[2 * q]));
                    float a1 = fmaf(xn0, Wa[2 * q + 1], fmaf(xn1, Wb[2 * q + 1], Bv[2 * q + 1]));
                    pk[q] = cvt_pk_bf16(fast_tanh(a0), fast_tanh(a1));
                }
                u32x4 pk0 = { pk[0], pk[1], pk[2], pk[3] };
                u32x4 pk1 = { pk[4], pk[5], pk[6], pk[7] };
                int base0 = (p << 5) + ((half * 16)     ^ SWZ(p));
                int base1 = (p << 5) + ((half * 16 + 8) ^ SWZ(p));
                *(u32x4*)&hb[base0] = pk0;
                *(u32x4*)&hb[base1] = pk1;
            }
            LDS_FENCE();

            const int ef0 = (p << 5) + ((half * 8)      ^ SWZ(p)); // k 0..15 slice
            const int ef1 = (p << 5) + ((16 + half * 8) ^ SWZ(p)); // k 16..31 slice

            // ---- layer 2 (MFMA) ----
            {
                bf16x8 bf0 = *(bf16x8*)&sW2t[si][ef0 & 1023];
                bf16x8 bf1 = *(bf16x8*)&sW2t[si][ef1 & 1023];
                bf16x8 a0  = *(bf16x8*)&hb[ef0];
                bf16x8 a1  = *(bf16x8*)&hb[ef1];
                float bj = sB2[si][p];
                f32x16 acc;
                #pragma unroll
                for (int r = 0; r < 16; ++r) acc[r] = bj;
                acc = __builtin_amdgcn_mfma_f32_32x32x16_bf16(a0, bf0, acc, 0, 0, 0);
                acc = __builtin_amdgcn_mfma_f32_32x32x16_bf16(a1, bf1, acc, 0, 0, 0);
                #pragma unroll
                for (int q = 0; q < 8; ++q) {
                    int r0 = 2 * q;
                    unsigned int pkv = cvt_pk_bf16(fast_tanh(acc[r0]), fast_tanh(acc[r0 + 1]));
                    int m0 = (r0 & 3) + ((r0 >> 2) << 3) + (half << 2);   // even
                    int a0i = (m0 << 5) + (p ^ SWZ(m0));
                    hb[a0i]      = (unsigned short)pkv;
                    hb[a0i + 32] = (unsigned short)(pkv >> 16);  // m0+1: same SWZ
                }
            }
            LDS_FENCE();

            // ---- layer 3 (MFMA) ----
            {
                bf16x8 bf0 = *(bf16x8*)&sW3t[si][ef0 & 1023];
                bf16x8 bf1 = *(bf16x8*)&sW3t[si][ef1 & 1023];
                bf16x8 a0  = *(bf16x8*)&hb[ef0];
                bf16x8 a1  = *(bf16x8*)&hb[ef1];
                float bj = sB3[si][p];
                f32x16 acc;
                #pragma unroll
                for (int r = 0; r < 16; ++r) acc[r] = bj;
                acc = __builtin_amdgcn_mfma_f32_32x32x16_bf16(a0, bf0, acc, 0, 0, 0);
                acc = __builtin_amdgcn_mfma_f32_32x32x16_bf16(a1, bf1, acc, 0, 0, 0);
                #pragma unroll
                for (int q = 0; q < 8; ++q) {
                    int r0 = 2 * q;
                    unsigned int pkv = cvt_pk_bf16(fast_tanh(acc[r0]), fast_tanh(acc[r0 + 1]));
                    int m0 = (r0 & 3) + ((r0 >> 2) << 3) + (half << 2);
                    int a0i = (m0 << 5) + (p ^ SWZ(m0));
                    hb[a0i]      = (unsigned short)pkv;
                    hb[a0i + 32] = (unsigned short)(pkv >> 16);
                }
            }
            LDS_FENCE();

            // ---- output dot (VALU) ----
            {
                int eo0 = (p << 5) + ((half * 16)     ^ SWZ(p));
                int eo1 = (p << 5) + ((half * 16 + 8) ^ SWZ(p));
                bf16x8 h3a = *(bf16x8*)&hb[eo0];
                bf16x8 h3b = *(bf16x8*)&hb[eo1];
                f32x4 wo0 = *(f32x4*)&sWo[si][half * 16 + 0];
                f32x4 wo1 = *(f32x4*)&sWo[si][half * 16 + 4];
                f32x4 wo2 = *(f32x4*)&sWo[si][half * 16 + 8];
                f32x4 wo3 = *(f32x4*)&sWo[si][half * 16 + 12];
                float Wo[16];
                #pragma unroll
                for (int i = 0; i < 4; ++i) {
                    Wo[i] = wo0[i]; Wo[4 + i] = wo1[i]; Wo[8 + i] = wo2[i]; Wo[12 + i] = wo3[i];
                }
                float yp = 0.0f;
                #pragma unroll
                for (int i = 0; i < 8; ++i)
                    yp = fmaf(__builtin_bit_cast(float, ((unsigned int)(unsigned short)h3a[i]) << 16), Wo[i], yp);
                #pragma unroll
                for (int i = 0; i < 8; ++i)
                    yp = fmaf(__builtin_bit_cast(float, ((unsigned int)(unsigned short)h3b[i]) << 16), Wo[8 + i], yp);
                float y = yp + __shfl_xor(yp, 32, 64);
                y += sBout[si];
                num = fmaf(w, y, num);
                den += w;
            }
        }
    }

    if (half == 0) {
        const int grp = blockIdx.y;
        ws[(size_t)(2 * grp)     * n_pts + P] = num;
        ws[(size_t)(2 * grp + 1) * n_pts + P] = den;
    }
}

// normalize + scale/shift + ansatz epilogue
__global__ __launch_bounds__(256) void fbpinn_combine(
    const float* __restrict__ X,
    const float* __restrict__ scale,
    const float* __restrict__ shift,
    const float* __restrict__ ws,
    float* __restrict__ out,
    int n_pts, int ngrp)
{
    const int P = blockIdx.x * 256 + threadIdx.x;
    if (P >= n_pts) return;
    float num = 0.0f, den = 0.0f;
    for (int g = 0; g < ngrp; ++g) {
        num += ws[(size_t)(2 * g)     * n_pts + P];
        den += ws[(size_t)(2 * g + 1) * n_pts + P];
    }
    // scale/shift are affine in y: sum w*(sc*y+sh) = sc*sum(w*y) + sh*sum(w)
    const float sc = scale[0], sh = shift[0];
    float u = fmaf(sc, num, sh * den) / (den + 1e-8f);
    const float t = X[2 * P + 0];
    const float x = X[2 * P + 1];
    float fac = fast_tanh(x + 1.0f) * fast_tanh(x - 1.0f) * fast_tanh(t);
    const float pi = 3.14159265358979323846f;
    out[P] = fmaf(fac, u, -__sinf(pi * x));
}

extern "C" void kernel_launch(void* const* d_in, const int* in_sizes, int n_in,
                              void* d_out, int out_size, void* d_ws, size_t ws_size,
                              hipStream_t stream) {
    const float* X        = (const float*)d_in[0];
    const float* centers  = (const float*)d_in[1];
    const float* widths   = (const float*)d_in[2];
    const float* core_min = (const float*)d_in[3];
    const float* core_max = (const float*)d_in[4];
    const float* overlap  = (const float*)d_in[5];
    const float* W1       = (const float*)d_in[6];
    const float* b1       = (const float*)d_in[7];
    const float* W2       = (const float*)d_in[8];
    const float* b2       = (const float*)d_in[9];
    const float* W3       = (const float*)d_in[10];
    const float* b3       = (const float*)d_in[11];
    const float* Wout     = (const float*)d_in[12];
    const float* bout     = (const float*)d_in[13];
    const float* scale    = (const float*)d_in[14];
    const float* shift    = (const float*)d_in[15];

    float* out = (float*)d_out;
    float* ws  = (float*)d_ws;
    const int n_pts = in_sizes[0] / 2;

    // pick most groups the workspace can hold (8 -> 8.4 MB at N=131072)
    int ngrp = 8;
    while (ngrp > 1 && (size_t)2 * ngrp * n_pts * sizeof(float) > ws_size) ngrp >>= 1;
    const int s_count = 32 / ngrp;

    dim3 grid((n_pts + 127) / 128, ngrp);
    fbpinn_main<<<grid, 256, 0, stream>>>(
        X, centers, widths, core_min, core_max, overlap,
        W1, b1, W2, b2, W3, b3, Wout, bout,
        ws, n_pts, s_count);

    fbpinn_combine<<<(n_pts + 255) / 256, 256, 0, stream>>>(
        X, scale, shift, ws, out, n_pts, ngrp);
}

// Round 6
// 249.979 us; speedup vs baseline: 3.0287x; 1.3905x over previous
//
#include <hip/hip_runtime.h>
#include <math.h>

typedef short    bf16x8 __attribute__((ext_vector_type(8)));
typedef float    f32x16 __attribute__((ext_vector_type(16)));
typedef float    f32x4  __attribute__((ext_vector_type(4)));
typedef unsigned int u32x4 __attribute__((ext_vector_type(4)));

// element-granular XOR swizzle: rows 2r,2r+1 share a swizzle; spreads 64B-stride
// rows across all 32 banks. SWZ in {0,8,16,24}.
#define SWZ(row) ((((row) >> 1) & 3) << 3)

__device__ __forceinline__ unsigned short f2bf(float f) {
    unsigned int u = __builtin_bit_cast(unsigned int, f);
    u = (u + 0x7FFFu + ((u >> 16) & 1u)) >> 16;   // RNE
    return (unsigned short)u;
}
__device__ __forceinline__ unsigned int cvt_pk_bf16(float lo, float hi) {
    unsigned int r;
    asm("v_cvt_pk_bf16_f32 %0, %1, %2" : "=v"(r) : "v"(lo), "v"(hi));
    return r;   // RNE
}
__device__ __forceinline__ float rcp_fast(float x) { return __builtin_amdgcn_rcpf(x); }

// tanh(z) = 1 - 2/(exp(2z)+1) with hardware rcp (1-ulp); saturates correctly.
__device__ __forceinline__ float tanh_f(float z) {
    return fmaf(-2.0f, rcp_fast(__expf(2.0f * z) + 1.0f), 1.0f);
}

// rule-18 fence: wave-local LDS write->read ordering
#define LDS_FENCE() do { \
    asm volatile("s_waitcnt lgkmcnt(0)" ::: "memory"); \
    __builtin_amdgcn_sched_barrier(0); \
} while (0)

// Each block: 128 points (4 waves x 32) x s_count subdomains (staged in
// chunks of 4). Partial (num, den) per point written to ws.
__global__ __launch_bounds__(256) void fbpinn_main(
    const float* __restrict__ X,
    const float* __restrict__ centers,
    const float* __restrict__ widths,
    const float* __restrict__ core_min,
    const float* __restrict__ core_max,
    const float* __restrict__ overlap,
    const float* __restrict__ W1,
    const float* __restrict__ b1,
    const float* __restrict__ W2,
    const float* __restrict__ b2,
    const float* __restrict__ W3,
    const float* __restrict__ b3,
    const float* __restrict__ Wout,
    const float* __restrict__ bout,
    float* __restrict__ ws,
    int n_pts, int s_count)
{
    __shared__ __align__(16) unsigned short sW2t[4][1024];  // swizzled [j][k], bf16
    __shared__ __align__(16) unsigned short sW3t[4][1024];
    __shared__ __align__(16) float sW1f[4][64];             // f32 [d][j]
    __shared__ __align__(16) float sB1[4][32], sB2[4][32], sB3[4][32], sWo[4][32];
    __shared__ float sBout[4];
    __shared__ __align__(16) unsigned short sH[4][1024];    // per-wave [pt][k] swizzled

    const int tid  = threadIdx.x;
    const int wave = tid >> 6;
    const int lane = tid & 63;
    const int p    = lane & 31;
    const int half = lane >> 5;
    const int s_begin = blockIdx.y * s_count;

    int P = blockIdx.x * 128 + wave * 32 + p;
    if (P >= n_pts) P = n_pts - 1;   // N divides exactly; safety only

    const float t = X[2 * P + 0];
    const float x = X[2 * P + 1];

    float num = 0.0f, den = 0.0f;
    unsigned short* hb = &sH[wave][0];

    // fragment offsets (loop-invariant)
    const int ef0 = (p << 5) + ((half * 8)      ^ SWZ(p)); // k 0..15 slice
    const int ef1 = (p << 5) + ((16 + half * 8) ^ SWZ(p)); // k 16..31 slice
    const int eo0 = (p << 5) + ((half * 16)     ^ SWZ(p));
    const int eo1 = (p << 5) + ((half * 16 + 8) ^ SWZ(p));

    for (int c0 = 0; c0 < s_count; c0 += 4) {
        __syncthreads();   // all waves done with previous chunk's weights
        // ---- stage 4 subdomains' weights (bf16 W2/W3, f32 W1 + biases) ----
        {
            const float* W2s = W2 + (size_t)(s_begin + c0) * 1024;
            const float* W3s = W3 + (size_t)(s_begin + c0) * 1024;
            #pragma unroll
            for (int i = 0; i < 16; ++i) {
                int e = tid + (i << 8);            // e = sl*1024 + k*32 + j
                int sl = e >> 10, r = e & 1023;
                int k = r >> 5, j = r & 31;
                int di = (j << 5) + (k ^ SWZ(j));  // transposed + swizzle
                sW2t[sl][di] = f2bf(W2s[e]);
                sW3t[sl][di] = f2bf(W3s[e]);
            }
            // W1: 4 subdomains x 64 f32 = 256 elements, one per thread
            sW1f[tid >> 6][tid & 63] = W1[(size_t)(s_begin + c0) * 64 + tid];
            if (tid < 128) {
                int sl = tid >> 5, j = tid & 31;
                int g = (s_begin + c0 + sl) * 32 + j;
                sB1[sl][j] = b1[g];
                sB2[sl][j] = b2[g];
                sB3[sl][j] = b3[g];
                sWo[sl][j] = Wout[g];
            }
            if (tid < 4) sBout[tid] = bout[s_begin + c0 + tid];
        }
        __syncthreads();

        for (int si = 0; si < 4; ++si) {
            const int s = s_begin + c0 + si;

            // ---- window + normalized coords (params wave-uniform -> s_load) ----
            float wid0 = widths[s * 2 + 0], wid1 = widths[s * 2 + 1];
            float sd0 = 4.0f * rcp_fast(fmaf(2.0f * overlap[s * 2 + 0], wid0, 1e-8f));
            float sd1 = 4.0f * rcp_fast(fmaf(2.0f * overlap[s * 2 + 1], wid1, 1e-8f));
            float z0 = sd0 * (t - core_min[s * 2 + 0]);
            float z1 = sd0 * (core_max[s * 2 + 0] - t);
            float z2 = sd1 * (x - core_min[s * 2 + 1]);
            float z3 = sd1 * (core_max[s * 2 + 1] - x);
            // product of 4 sigmoids = rcp of product of (1+e^-z); factors >= 1
            float w = rcp_fast(((1.0f + __expf(-z0)) * (1.0f + __expf(-z1)))
                             * ((1.0f + __expf(-z2)) * (1.0f + __expf(-z3))));
            float xn0 = (t - centers[s * 2 + 0]) * rcp_fast(wid0) + 0.5f;
            float xn1 = (x - centers[s * 2 + 1]) * rcp_fast(wid1) + 0.5f;

            // ---- layer 1 (VALU, f32 weights): j = half*16 + 0..15 ----
            {
                const f32x4* Wa4 = (const f32x4*)&sW1f[si][half * 16];        // d0
                const f32x4* Wb4 = (const f32x4*)&sW1f[si][32 + half * 16];   // d1
                const f32x4* Bv4 = (const f32x4*)&sB1[si][half * 16];
                float Wa[16], Wb[16], Bv[16];
                #pragma unroll
                for (int i = 0; i < 4; ++i) {
                    f32x4 av = Wa4[i], bv = Wb4[i], cv = Bv4[i];
                    #pragma unroll
                    for (int q = 0; q < 4; ++q) {
                        Wa[4 * i + q] = av[q];
                        Wb[4 * i + q] = bv[q];
                        Bv[4 * i + q] = cv[q];
                    }
                }
                unsigned int pk[8];
                #pragma unroll
                for (int q = 0; q < 8; ++q) {
                    float a0 = fmaf(xn0, Wa[2 * q],     fmaf(xn1, Wb[2 * q],     Bv[2 * q]));
                    float a1 = fmaf(xn0, Wa[2 * q + 1], fmaf(xn1, Wb[2 * q + 1], Bv[2 * q + 1]));
                    pk[q] = cvt_pk_bf16(tanh_f(a0), tanh_f(a1));
                }
                u32x4 pk0 = { pk[0], pk[1], pk[2], pk[3] };
                u32x4 pk1 = { pk[4], pk[5], pk[6], pk[7] };
                int base0 = (p << 5) + ((half * 16)     ^ SWZ(p));
                int base1 = (p << 5) + ((half * 16 + 8) ^ SWZ(p));
                *(u32x4*)&hb[base0] = pk0;
                *(u32x4*)&hb[base1] = pk1;
            }
            LDS_FENCE();

            // ---- layer 2 (MFMA) ----
            {
                bf16x8 bf0 = *(bf16x8*)&sW2t[si][ef0];
                bf16x8 bf1 = *(bf16x8*)&sW2t[si][ef1];
                bf16x8 a0  = *(bf16x8*)&hb[ef0];
                bf16x8 a1  = *(bf16x8*)&hb[ef1];
                float bj = sB2[si][p];
                f32x16 acc;
                #pragma unroll
                for (int r = 0; r < 16; ++r) acc[r] = bj;
                acc = __builtin_amdgcn_mfma_f32_32x32x16_bf16(a0, bf0, acc, 0, 0, 0);
                acc = __builtin_amdgcn_mfma_f32_32x32x16_bf16(a1, bf1, acc, 0, 0, 0);
                #pragma unroll
                for (int q = 0; q < 8; ++q) {
                    int r0 = 2 * q;
                    unsigned int pkv = cvt_pk_bf16(tanh_f(acc[r0]), tanh_f(acc[r0 + 1]));
                    int m0 = (r0 & 3) + ((r0 >> 2) << 3) + (half << 2);   // even
                    int ai = (m0 << 5) + (p ^ SWZ(m0));
                    hb[ai]      = (unsigned short)pkv;
                    hb[ai + 32] = (unsigned short)(pkv >> 16);  // m0+1 shares SWZ
                }
            }
            LDS_FENCE();

            // ---- layer 3 (MFMA) ----
            {
                bf16x8 bf0 = *(bf16x8*)&sW3t[si][ef0];
                bf16x8 bf1 = *(bf16x8*)&sW3t[si][ef1];
                bf16x8 a0  = *(bf16x8*)&hb[ef0];
                bf16x8 a1  = *(bf16x8*)&hb[ef1];
                float bj = sB3[si][p];
                f32x16 acc;
                #pragma unroll
                for (int r = 0; r < 16; ++r) acc[r] = bj;
                acc = __builtin_amdgcn_mfma_f32_32x32x16_bf16(a0, bf0, acc, 0, 0, 0);
                acc = __builtin_amdgcn_mfma_f32_32x32x16_bf16(a1, bf1, acc, 0, 0, 0);
                #pragma unroll
                for (int q = 0; q < 8; ++q) {
                    int r0 = 2 * q;
                    unsigned int pkv = cvt_pk_bf16(tanh_f(acc[r0]), tanh_f(acc[r0 + 1]));
                    int m0 = (r0 & 3) + ((r0 >> 2) << 3) + (half << 2);
                    int ai = (m0 << 5) + (p ^ SWZ(m0));
                    hb[ai]      = (unsigned short)pkv;
                    hb[ai + 32] = (unsigned short)(pkv >> 16);
                }
            }
            LDS_FENCE();

            // ---- output dot (VALU) ----
            {
                bf16x8 h3a = *(bf16x8*)&hb[eo0];
                bf16x8 h3b = *(bf16x8*)&hb[eo1];
                f32x4 wo0 = *(f32x4*)&sWo[si][half * 16 + 0];
                f32x4 wo1 = *(f32x4*)&sWo[si][half * 16 + 4];
                f32x4 wo2 = *(f32x4*)&sWo[si][half * 16 + 8];
                f32x4 wo3 = *(f32x4*)&sWo[si][half * 16 + 12];
                float Wo[16];
                #pragma unroll
                for (int i = 0; i < 4; ++i) {
                    Wo[i] = wo0[i]; Wo[4 + i] = wo1[i]; Wo[8 + i] = wo2[i]; Wo[12 + i] = wo3[i];
                }
                float yp = 0.0f;
                #pragma unroll
                for (int i = 0; i < 8; ++i)
                    yp = fmaf(__builtin_bit_cast(float, ((unsigned int)(unsigned short)h3a[i]) << 16), Wo[i], yp);
                #pragma unroll
                for (int i = 0; i < 8; ++i)
                    yp = fmaf(__builtin_bit_cast(float, ((unsigned int)(unsigned short)h3b[i]) << 16), Wo[8 + i], yp);
                float y = yp + __shfl_xor(yp, 32, 64);   // combine hidden halves
                y += sBout[si];
                num = fmaf(w, y, num);
                den += w;
            }
        }
    }

    if (half == 0) {
        const int grp = blockIdx.y;
        ws[(size_t)(2 * grp)     * n_pts + P] = num;
        ws[(size_t)(2 * grp + 1) * n_pts + P] = den;
    }
}

// normalize + scale/shift + ansatz epilogue
__global__ __launch_bounds__(256) void fbpinn_combine(
    const float* __restrict__ X,
    const float* __restrict__ scale,
    const float* __restrict__ shift,
    const float* __restrict__ ws,
    float* __restrict__ out,
    int n_pts, int ngrp)
{
    const int P = blockIdx.x * 256 + threadIdx.x;
    if (P >= n_pts) return;
    float num = 0.0f, den = 0.0f;
    for (int g = 0; g < ngrp; ++g) {
        num += ws[(size_t)(2 * g)     * n_pts + P];
        den += ws[(size_t)(2 * g + 1) * n_pts + P];
    }
    // scale/shift are affine in y: sum w*(sc*y+sh) = sc*sum(w*y) + sh*sum(w)
    const float sc = scale[0], sh = shift[0];
    float u = fmaf(sc, num, sh * den) / (den + 1e-8f);
    const float t = X[2 * P + 0];
    const float x = X[2 * P + 1];
    float fac = tanh_f(x + 1.0f) * tanh_f(x - 1.0f) * tanh_f(t);
    const float pi = 3.14159265358979323846f;
    out[P] = fmaf(fac, u, -__sinf(pi * x));
}

extern "C" void kernel_launch(void* const* d_in, const int* in_sizes, int n_in,
                              void* d_out, int out_size, void* d_ws, size_t ws_size,
                              hipStream_t stream) {
    const float* X        = (const float*)d_in[0];
    const float* centers  = (const float*)d_in[1];
    const float* widths   = (const float*)d_in[2];
    const float* core_min = (const float*)d_in[3];
    const float* core_max = (const float*)d_in[4];
    const float* overlap  = (const float*)d_in[5];
    const float* W1       = (const float*)d_in[6];
    const float* b1       = (const float*)d_in[7];
    const float* W2       = (const float*)d_in[8];
    const float* b2       = (const float*)d_in[9];
    const float* W3       = (const float*)d_in[10];
    const float* b3       = (const float*)d_in[11];
    const float* Wout     = (const float*)d_in[12];
    const float* bout     = (const float*)d_in[13];
    const float* scale    = (const float*)d_in[14];
    const float* shift    = (const float*)d_in[15];

    float* out = (float*)d_out;
    float* ws  = (float*)d_ws;
    const int n_pts = in_sizes[0] / 2;

    int ngrp = 8;
    while (ngrp > 1 && (size_t)2 * ngrp * n_pts * sizeof(float) > ws_size) ngrp >>= 1;
    const int s_count = 32 / ngrp;

    dim3 grid((n_pts + 127) / 128, ngrp);
    fbpinn_main<<<grid, 256, 0, stream>>>(
        X, centers, widths, core_min, core_max, overlap,
        W1, b1, W2, b2, W3, b3, Wout, bout,
        ws, n_pts, s_count);

    fbpinn_combine<<<(n_pts + 255) / 256, 256, 0, stream>>>(
        X, scale, shift, ws, out, n_pts, ngrp);
}

// Round 8
// 211.880 us; speedup vs baseline: 3.5733x; 1.1798x over previous
//
#include <hip/hip_runtime.h>
#include <math.h>

typedef short    bf16x8 __attribute__((ext_vector_type(8)));
typedef float    f32x16 __attribute__((ext_vector_type(16)));
typedef float    f32x4  __attribute__((ext_vector_type(4)));
typedef unsigned int u32x4 __attribute__((ext_vector_type(4)));

// element-granular XOR swizzle for the weight tiles (64B-stride rows -> all banks)
#define SWZ(row) ((((row) >> 1) & 3) << 3)

__device__ __forceinline__ unsigned short f2bf(float f) {
    unsigned int u = __builtin_bit_cast(unsigned int, f);
    u = (u + 0x7FFFu + ((u >> 16) & 1u)) >> 16;   // RNE
    return (unsigned short)u;
}
__device__ __forceinline__ unsigned int cvt_pk_bf16(float lo, float hi) {
    unsigned int r;
    asm("v_cvt_pk_bf16_f32 %0, %1, %2" : "=v"(r) : "v"(lo), "v"(hi));
    return r;   // RNE
}
__device__ __forceinline__ float rcp_fast(float x) { return __builtin_amdgcn_rcpf(x); }

// tanh(z) = 1 - 2/(exp(2z)+1) with hardware rcp (1-ulp); saturates correctly.
__device__ __forceinline__ float tanh_f(float z) {
    return fmaf(-2.0f, rcp_fast(__expf(2.0f * z) + 1.0f), 1.0f);
}
__device__ __forceinline__ unsigned int sx32(unsigned int v) {
    return (unsigned int)__shfl_xor((int)v, 32, 64);
}

// Each block: 128 points (4 waves x 32) x s_count subdomains (staged in
// chunks of 4). Partial (num, den) per point written to ws.
// MFMA scheme (swapped operands): D = W^T (A, from LDS) x h^T (B, in regs).
// D col = lane&31 = point, D rows = neurons (reg formula) -> activations stay
// in registers across layers; half-exchange via shfl_xor(32).
__global__ __launch_bounds__(256) void fbpinn_main(
    const float* __restrict__ X,
    const float* __restrict__ centers,
    const float* __restrict__ widths,
    const float* __restrict__ core_min,
    const float* __restrict__ core_max,
    const float* __restrict__ overlap,
    const float* __restrict__ W1,
    const float* __restrict__ b1,
    const float* __restrict__ W2,
    const float* __restrict__ b2,
    const float* __restrict__ W3,
    const float* __restrict__ b3,
    const float* __restrict__ Wout,
    const float* __restrict__ bout,
    float* __restrict__ ws,
    int n_pts, int s_count)
{
    __shared__ __align__(16) unsigned short sW2t[4][1024];  // swizzled [j][k], bf16
    __shared__ __align__(16) unsigned short sW3t[4][1024];
    __shared__ __align__(16) float sW1f[4][64];             // f32 [d][j]
    __shared__ __align__(16) float sB1[4][32], sB2[4][32], sB3[4][32], sWo[4][32];
    __shared__ float sBout[4];

    const int tid  = threadIdx.x;
    const int wave = tid >> 6;
    const int lane = tid & 63;
    const int p    = lane & 31;   // point id within wave; also MFMA D-col
    const int hi   = lane >> 5;   // half selector
    const int s_begin = blockIdx.y * s_count;

    int P = blockIdx.x * 128 + wave * 32 + p;
    if (P >= n_pts) P = n_pts - 1;   // N divides exactly; safety only

    const float t = X[2 * P + 0];
    const float x = X[2 * P + 1];

    float num = 0.0f, den = 0.0f;

    // weight-fragment offsets (A-operand = W^T, row = p as neuron, k-slices)
    const int ef0 = (p << 5) + ((hi * 8)      ^ SWZ(p)); // k 0..15 slice
    const int ef1 = (p << 5) + ((16 + hi * 8) ^ SWZ(p)); // k 16..31 slice

    for (int c0 = 0; c0 < s_count; c0 += 4) {
        __syncthreads();
        // ---- stage 4 subdomains' weights (bf16 W2/W3, f32 W1 + biases) ----
        {
            const float* W2s = W2 + (size_t)(s_begin + c0) * 1024;
            const float* W3s = W3 + (size_t)(s_begin + c0) * 1024;
            #pragma unroll
            for (int i = 0; i < 16; ++i) {
                int e = tid + (i << 8);            // e = sl*1024 + k*32 + j
                int sl = e >> 10, r = e & 1023;
                int k = r >> 5, j = r & 31;
                int di = (j << 5) + (k ^ SWZ(j));  // transposed + swizzle
                sW2t[sl][di] = f2bf(W2s[e]);
                sW3t[sl][di] = f2bf(W3s[e]);
            }
            sW1f[tid >> 6][tid & 63] = W1[(size_t)(s_begin + c0) * 64 + tid];
            if (tid < 128) {
                int sl = tid >> 5, j = tid & 31;
                int g = (s_begin + c0 + sl) * 32 + j;
                sB1[sl][j] = b1[g];
                sB2[sl][j] = b2[g];
                sB3[sl][j] = b3[g];
                sWo[sl][j] = Wout[g];
            }
            if (tid < 4) sBout[tid] = bout[s_begin + c0 + tid];
        }
        __syncthreads();

        for (int si = 0; si < 4; ++si) {
            const int s = s_begin + c0 + si;

            // ---- window + normalized coords (wave-uniform s_loads) ----
            float wid0 = widths[s * 2 + 0], wid1 = widths[s * 2 + 1];
            float sd0 = 4.0f * rcp_fast(fmaf(2.0f * overlap[s * 2 + 0], wid0, 1e-8f));
            float sd1 = 4.0f * rcp_fast(fmaf(2.0f * overlap[s * 2 + 1], wid1, 1e-8f));
            float z0 = sd0 * (t - core_min[s * 2 + 0]);
            float z1 = sd0 * (core_max[s * 2 + 0] - t);
            float z2 = sd1 * (x - core_min[s * 2 + 1]);
            float z3 = sd1 * (core_max[s * 2 + 1] - x);
            float w = rcp_fast(((1.0f + __expf(-z0)) * (1.0f + __expf(-z1)))
                             * ((1.0f + __expf(-z2)) * (1.0f + __expf(-z3))));
            float xn0 = (t - centers[s * 2 + 0]) * rcp_fast(wid0) + 0.5f;
            float xn1 = (x - centers[s * 2 + 1]) * rcp_fast(wid1) + 0.5f;

            unsigned int pk[8];

            // ---- layer 1 (VALU): lane (p,hi) computes neurons j = 16*hi..+15 ----
            {
                const f32x4* Wa4 = (const f32x4*)&sW1f[si][hi * 16];        // d0
                const f32x4* Wb4 = (const f32x4*)&sW1f[si][32 + hi * 16];   // d1
                const f32x4* Bv4 = (const f32x4*)&sB1[si][hi * 16];
                float Wa[16], Wb[16], Bv[16];
                #pragma unroll
                for (int i = 0; i < 4; ++i) {
                    f32x4 av = Wa4[i], bv = Wb4[i], cv = Bv4[i];
                    #pragma unroll
                    for (int q = 0; q < 4; ++q) {
                        Wa[4 * i + q] = av[q];
                        Wb[4 * i + q] = bv[q];
                        Bv[4 * i + q] = cv[q];
                    }
                }
                #pragma unroll
                for (int q = 0; q < 8; ++q) {
                    float a0 = fmaf(xn0, Wa[2 * q],     fmaf(xn1, Wb[2 * q],     Bv[2 * q]));
                    float a1 = fmaf(xn0, Wa[2 * q + 1], fmaf(xn1, Wb[2 * q + 1], Bv[2 * q + 1]));
                    pk[q] = cvt_pk_bf16(tanh_f(a0), tanh_f(a1));
                }
            }
            // exchange: hi=0 sends j8..15 (pk4..7), hi=1 sends j16..23 (pk0..3)
            bf16x8 Bf0, Bf1;
            {
                unsigned int r0 = sx32(hi ? pk[0] : pk[4]);
                unsigned int r1 = sx32(hi ? pk[1] : pk[5]);
                unsigned int r2 = sx32(hi ? pk[2] : pk[6]);
                unsigned int r3 = sx32(hi ? pk[3] : pk[7]);
                u32x4 f1 = hi ? (u32x4){r0, r1, r2, r3} : (u32x4){pk[0], pk[1], pk[2], pk[3]};
                u32x4 f2 = hi ? (u32x4){pk[4], pk[5], pk[6], pk[7]} : (u32x4){r0, r1, r2, r3};
                Bf0 = __builtin_bit_cast(bf16x8, f1);
                Bf1 = __builtin_bit_cast(bf16x8, f2);
            }

            // ---- layer 2 (MFMA, swapped): D2[j][m] ----
            f32x16 acc;
            {
                bf16x8 A0 = *(bf16x8*)&sW2t[si][ef0];
                bf16x8 A1 = *(bf16x8*)&sW2t[si][ef1];
                #pragma unroll
                for (int i = 0; i < 4; ++i) {
                    f32x4 bv = *(const f32x4*)&sB2[si][8 * i + 4 * hi];
                    #pragma unroll
                    for (int q = 0; q < 4; ++q) acc[4 * i + q] = bv[q];
                }
                acc = __builtin_amdgcn_mfma_f32_32x32x16_bf16(A0, Bf0, acc, 0, 0, 0);
                acc = __builtin_amdgcn_mfma_f32_32x32x16_bf16(A1, Bf1, acc, 0, 0, 0);
            }
            // tanh + pack: pk[q] = neurons (j(2q), j(2q)+1), j(r)=(r&3)+8(r>>2)+4hi
            #pragma unroll
            for (int q = 0; q < 8; ++q)
                pk[q] = cvt_pk_bf16(tanh_f(acc[2 * q]), tanh_f(acc[2 * q + 1]));
            // exchange: hi=0 sends pk2,3 (j8..11) & pk6,7 (j24..27);
            //           hi=1 sends pk0,1 (j4..7)  & pk4,5 (j20..23)
            {
                unsigned int r0 = sx32(hi ? pk[0] : pk[2]);
                unsigned int r1 = sx32(hi ? pk[1] : pk[3]);
                unsigned int r2 = sx32(hi ? pk[4] : pk[6]);
                unsigned int r3 = sx32(hi ? pk[5] : pk[7]);
                u32x4 f1 = hi ? (u32x4){r0, r1, pk[2], pk[3]} : (u32x4){pk[0], pk[1], r0, r1};
                u32x4 f2 = hi ? (u32x4){r2, r3, pk[6], pk[7]} : (u32x4){pk[4], pk[5], r2, r3};
                Bf0 = __builtin_bit_cast(bf16x8, f1);
                Bf1 = __builtin_bit_cast(bf16x8, f2);
            }

            // ---- layer 3 (MFMA, swapped) ----
            {
                bf16x8 A0 = *(bf16x8*)&sW3t[si][ef0];
                bf16x8 A1 = *(bf16x8*)&sW3t[si][ef1];
                #pragma unroll
                for (int i = 0; i < 4; ++i) {
                    f32x4 bv = *(const f32x4*)&sB3[si][8 * i + 4 * hi];
                    #pragma unroll
                    for (int q = 0; q < 4; ++q) acc[4 * i + q] = bv[q];
                }
                acc = __builtin_amdgcn_mfma_f32_32x32x16_bf16(A0, Bf0, acc, 0, 0, 0);
                acc = __builtin_amdgcn_mfma_f32_32x32x16_bf16(A1, Bf1, acc, 0, 0, 0);
            }

            // ---- output dot: y[p] = sum_j tanh(h3[p][j]) * Wout[j] ----
            {
                float yp = 0.0f;
                #pragma unroll
                for (int i = 0; i < 4; ++i) {
                    f32x4 wv = *(const f32x4*)&sWo[si][8 * i + 4 * hi];
                    #pragma unroll
                    for (int q = 0; q < 4; ++q)
                        yp = fmaf(tanh_f(acc[4 * i + q]), wv[q], yp);
                }
                float y = yp + __shfl_xor(yp, 32, 64);   // combine both halves
                y += sBout[si];
                num = fmaf(w, y, num);
                den += w;
            }
        }
    }

    if (hi == 0) {
        const int grp = blockIdx.y;
        ws[(size_t)(2 * grp)     * n_pts + P] = num;
        ws[(size_t)(2 * grp + 1) * n_pts + P] = den;
    }
}

// normalize + scale/shift + ansatz epilogue
__global__ __launch_bounds__(256) void fbpinn_combine(
    const float* __restrict__ X,
    const float* __restrict__ scale,
    const float* __restrict__ shift,
    const float* __restrict__ ws,
    float* __restrict__ out,
    int n_pts, int ngrp)
{
    const int P = blockIdx.x * 256 + threadIdx.x;
    if (P >= n_pts) return;
    float num = 0.0f, den = 0.0f;
    for (int g = 0; g < ngrp; ++g) {
        num += ws[(size_t)(2 * g)     * n_pts + P];
        den += ws[(size_t)(2 * g + 1) * n_pts + P];
    }
    // scale/shift are affine in y: sum w*(sc*y+sh) = sc*sum(w*y) + sh*sum(w)
    const float sc = scale[0], sh = shift[0];
    float u = fmaf(sc, num, sh * den) / (den + 1e-8f);
    const float t = X[2 * P + 0];
    const float x = X[2 * P + 1];
    float fac = tanh_f(x + 1.0f) * tanh_f(x - 1.0f) * tanh_f(t);
    const float pi = 3.14159265358979323846f;
    out[P] = fmaf(fac, u, -__sinf(pi * x));
}

extern "C" void kernel_launch(void* const* d_in, const int* in_sizes, int n_in,
                              void* d_out, int out_size, void* d_ws, size_t ws_size,
                              hipStream_t stream) {
    const float* X        = (const float*)d_in[0];
    const float* centers  = (const float*)d_in[1];
    const float* widths   = (const float*)d_in[2];
    const float* core_min = (const float*)d_in[3];
    const float* core_max = (const float*)d_in[4];
    const float* overlap  = (const float*)d_in[5];
    const float* W1       = (const float*)d_in[6];
    const float* b1       = (const float*)d_in[7];
    const float* W2       = (const float*)d_in[8];
    const float* b2       = (const float*)d_in[9];
    const float* W3       = (const float*)d_in[10];
    const float* b3       = (const float*)d_in[11];
    const float* Wout     = (const float*)d_in[12];
    const float* bout     = (const float*)d_in[13];
    const float* scale    = (const float*)d_in[14];
    const float* shift    = (const float*)d_in[15];

    float* out = (float*)d_out;
    float* ws  = (float*)d_ws;
    const int n_pts = in_sizes[0] / 2;

    int ngrp = 8;
    while (ngrp > 1 && (size_t)2 * ngrp * n_pts * sizeof(float) > ws_size) ngrp >>= 1;
    const int s_count = 32 / ngrp;

    dim3 grid((n_pts + 127) / 128, ngrp);
    fbpinn_main<<<grid, 256, 0, stream>>>(
        X, centers, widths, core_min, core_max, overlap,
        W1, b1, W2, b2, W3, b3, Wout, bout,
        ws, n_pts, s_count);

    fbpinn_combine<<<(n_pts + 255) / 256, 256, 0, stream>>>(
        X, scale, shift, ws, out, n_pts, ngrp);
}